// Round 11
// baseline (284.256 us; speedup 1.0000x reference)
//
#include <hip/hip_runtime.h>
#include <math.h>

#define NB 8
#define CIN 256
#define CR 64
#define H 64
#define W 64
#define HW 4096

typedef _Float16 f16;
typedef _Float16 f16x8 __attribute__((ext_vector_type(8)));
typedef _Float16 f16x4 __attribute__((ext_vector_type(4)));
typedef float f32x4 __attribute__((ext_vector_type(4)));

static const size_t QKV = (size_t)NB * CR * HW;   // 2,097,152 elems per q/k/v buffer

// async global->LDS, 16B per lane, LDS dest = uniform base + lane*16
static __device__ __forceinline__ void gl_lds16(const f16* g, f16* l) {
    __builtin_amdgcn_global_load_lds(
        (const __attribute__((address_space(1))) void*)g,
        (__attribute__((address_space(3))) void*)l, 16, 0, 0);
}

// raw v_exp_f32 (exp2); inputs are <= 0 here, denorm tail irrelevant
static __device__ __forceinline__ float ex2(float x) {
    return __builtin_amdgcn_exp2f(x);
}

// ------------------------------------------------------------- weight prep
// w[co][ci][dy][dx] fp32 -> wT[dy*K+dx][co][ci] fp16
__global__ __launch_bounds__(256) void prep_w(
    const float* __restrict__ src, f16* __restrict__ dst, int KK)
{
    int idx = blockIdx.x * 256 + threadIdx.x;    // < 64*256*KK
    int ci = idx & 255;
    int co = (idx >> 8) & 63;
    int off = idx >> 14;
    dst[((size_t)(off * 64 + co)) * 256 + ci] = (f16)src[((size_t)(co * 256 + ci)) * KK + off];
}

// ------------------------------------------------------- feature-map transpose
// fm f32 [n][ci][y][x] -> fmT f16 [n][y*64+x][ci]
__global__ __launch_bounds__(256) void transpose_fm(
    const float* __restrict__ fm, f16* __restrict__ fmT)
{
    const int y = blockIdx.x & 63;
    const int n = blockIdx.x >> 6;
    const int tid = threadIdx.x;
    __shared__ f16x4 tile[64 * 64];   // [x][slot], slot XOR-swizzled by x
    const int xw = tid & 63;
    const int wv = tid >> 6;
    const float* s0 = fm + ((size_t)n * CIN) * HW + y * W + xw;
#pragma unroll
    for (int cc = 0; cc < 16; ++cc) {
        const int slot = wv * 16 + cc;            // ci = slot*4 + e
        const float* s = s0 + (size_t)(slot * 4) * HW;
        f16x4 pk;
#pragma unroll
        for (int e = 0; e < 4; ++e) pk[e] = (f16)s[(size_t)e * HW];
        tile[xw * 64 + (slot ^ xw)] = pk;
    }
    __syncthreads();
    f16x4* dst = (f16x4*)fmT + ((size_t)n * HW + y * W) * 64;
#pragma unroll
    for (int it = 0; it < 16; ++it) {
        const int idx = tid + it * 256;           // < 4096
        const int x = idx >> 6;
        const int slot = idx & 63;
        dst[x * 64 + slot] = tile[x * 64 + (slot ^ x)];
    }
}

// ---------------------------------------------------------- MFMA conv K x K
// Grid 256 blocks (n, 2-row group), 512 threads = 8 waves (row r, co-half h, k-half sw).
// LAYOUT 0: dst [n][p][c] f16 (q, k).  LAYOUT 1: dst [n][c][p] f16 (v).
// oscale: output scale (log2e for q to move softmax into exp2 domain).
template<int K, int LAYOUT>
__global__ __launch_bounds__(512) void conv_mfma(
    const f16* __restrict__ fmT, const f16* __restrict__ wT,
    const float* __restrict__ bias, f16* __restrict__ dst, float oscale)
{
    constexpr int P = K / 2;
    constexpr int XBYTES = 2 * 72 * 128;          // 18432
    constexpr int WBYTES = K * 64 * 128;
    constexpr int TBYTES = XBYTES + WBYTES;
    constexpr int SBYTES = (TBYTES > 32768) ? TBYTES : 32768;
    __shared__ __align__(16) unsigned char smem[SBYTES];
    unsigned char* Xl = smem;
    unsigned char* Wl = smem + XBYTES;

    const int bid0 = blockIdx.x;
    const int bid = (bid0 & 7) * 32 + (bid0 >> 3);   // XCD swizzle, 256 = 8*32
    const int n  = bid >> 5;
    const int y0 = (bid & 31) * 2;
    const int tid = threadIdx.x;
    const int w = tid >> 6;
    const int lane = tid & 63;
    const int r  = w >> 2;        // row within block
    const int h  = (w >> 1) & 1;  // co half
    const int sw = w & 1;         // k half (32-ci sub-chunk)
    const int lm = lane & 15;
    const int g  = lane >> 4;

    // zero halo columns once (cols [0,P) and [64+P,72) of both slots)
    if (tid < 128) {
        const int sl = tid >> 6;
        const int cidx = (tid >> 3) & 7;
        const int chunk = tid & 7;
        const int col = (cidx < P) ? cidx : (64 + cidx);
        *(uint4*)(Xl + (size_t)(sl * 72 + col) * 128 + chunk * 16) = uint4{0, 0, 0, 0};
    }

    f32x4 acc[2][4];
#pragma unroll
    for (int i = 0; i < 2; ++i)
#pragma unroll
        for (int jx = 0; jx < 4; ++jx) acc[i][jx] = f32x4{0.f, 0.f, 0.f, 0.f};

    for (int dy = 0; dy < K; ++dy) {
        for (int ch = 0; ch < 4; ++ch) {
            __syncthreads();
            // ---- stage X: 2 rows x 64 x x 64 ci(ch) = 1024 uint4, 2/thread
#pragma unroll
            for (int p = 0; p < 2; ++p) {
                const int idx = tid + p * 512;
                const int sl = idx >> 9;
                const int x = (idx >> 3) & 63;
                const int chunk = idx & 7;
                const int iy = y0 + sl + dy - P;
                uint4 val = uint4{0, 0, 0, 0};
                if (iy >= 0 && iy < H)
                    val = *(const uint4*)(fmT + ((size_t)n * HW + iy * 64 + x) * 256 +
                                          ch * 64 + chunk * 8);
                *(uint4*)(Xl + (size_t)(sl * 72 + x + P) * 128 +
                          ((chunk * 16) ^ (((x + P) & 7) << 4))) = val;
            }
            // ---- stage W: K*512 uint4, K/thread
#pragma unroll
            for (int p = 0; p < K; ++p) {
                const int idx = tid + p * 512;
                const int cig = idx & 7;
                const int co  = (idx >> 3) & 63;
                const int dx  = idx >> 9;
                const f16* s = wT + ((size_t)((dy * K + dx) * 64 + co)) * 256 + ch * 64 + cig * 8;
                *(uint4*)(Wl + (size_t)(dx * 64 + co) * 128 +
                          ((cig * 16) ^ ((co & 7) << 4))) = *(const uint4*)s;
            }
            __syncthreads();
            // ---- compute
#pragma unroll
            for (int dx = 0; dx < K; ++dx) {
                f16x8 a[2], b[4];
#pragma unroll
                for (int cf = 0; cf < 2; ++cf) {
                    const int co = h * 32 + cf * 16 + lm;
                    a[cf] = *(const f16x8*)(Wl + (size_t)(dx * 64 + co) * 128 +
                                            ((sw * 64 + g * 16) ^ ((co & 7) << 4)));
                }
#pragma unroll
                for (int xf = 0; xf < 4; ++xf) {
                    const int col = xf * 16 + lm + dx;
                    b[xf] = *(const f16x8*)(Xl + (size_t)(r * 72 + col) * 128 +
                                            ((sw * 64 + g * 16) ^ ((col & 7) << 4)));
                }
#pragma unroll
                for (int cf = 0; cf < 2; ++cf)
#pragma unroll
                    for (int xf = 0; xf < 4; ++xf)
                        acc[cf][xf] = __builtin_amdgcn_mfma_f32_16x16x32_f16(
                            a[cf], b[xf], acc[cf][xf], 0, 0, 0);
            }
        }
    }

    // ---- merge k-halves
    __syncthreads();
    {
        const int mslot = r * 2 + h;
        if (sw == 1) {
#pragma unroll
            for (int cf = 0; cf < 2; ++cf)
#pragma unroll
                for (int xf = 0; xf < 4; ++xf)
                    *(f32x4*)(smem + (size_t)(mslot * 64 + lane) * 128 +
                              (((cf * 4 + xf) * 16) ^ ((lane & 7) << 4))) = acc[cf][xf];
        }
        __syncthreads();
        if (sw == 0) {
#pragma unroll
            for (int cf = 0; cf < 2; ++cf)
#pragma unroll
                for (int xf = 0; xf < 4; ++xf)
                    acc[cf][xf] += *(const f32x4*)(smem + (size_t)(mslot * 64 + lane) * 128 +
                                                   (((cf * 4 + xf) * 16) ^ ((lane & 7) << 4)));
        }
    }

    // ---- epilogue (sw=0 waves)
    if (sw == 0) {
        const int y = y0 + r;
#pragma unroll
        for (int cf = 0; cf < 2; ++cf) {
            const float4 bv = *(const float4*)(bias + h * 32 + cf * 16 + g * 4);
            if (LAYOUT == 0) {
#pragma unroll
                for (int xf = 0; xf < 4; ++xf) {
                    f16x4 pk;
#pragma unroll
                    for (int e = 0; e < 4; ++e)
                        pk[e] = (f16)((acc[cf][xf][e] + ((const float*)&bv)[e]) * oscale);
                    *(f16x4*)(dst + ((size_t)n * HW + y * W + xf * 16 + lm) * 64 +
                              h * 32 + cf * 16 + g * 4) = pk;
                }
            } else {
#pragma unroll
                for (int e = 0; e < 4; ++e) {
                    const int co = h * 32 + cf * 16 + g * 4 + e;
#pragma unroll
                    for (int xf = 0; xf < 4; ++xf)
                        dst[((size_t)(n * CR + co)) * HW + y * W + xf * 16 + lm] =
                            (f16)((acc[cf][xf][e] + ((const float*)&bv)[e]) * oscale);
                }
            }
        }
    }
}

// ------------------------------------------------- fused MFMA attention (16x16)
// Grid 512 (n, 64-j tile), 512 threads = 8 waves. Waves 0-3 process i in [0,2048),
// waves 4-7 process [2048,4096). K A-frags read DIRECTLY from global (L2-resident,
// both co-resident blocks share n -> L1 hits); V double-buffered in LDS via
// global_load_lds. Online softmax state in registers; one-time merge via LDS.
__global__ __launch_bounds__(512, 4) void attn_mfma(
    const f16* __restrict__ qT, const f16* __restrict__ kT, const f16* __restrict__ vv,
    f16* __restrict__ attu, float* __restrict__ Mcol, float* __restrict__ Zcol)
{
    const int bid0 = blockIdx.x;
    const int bid = (bid0 & 7) * 64 + (bid0 >> 3);   // XCD swizzle: n == XCD
    const int jt = bid & 63;
    const int n  = bid >> 6;
    const int tid = threadIdx.x;
    const int wv = tid >> 6;       // 0..7
    const int ih = wv >> 2;        // i-half
    const int wl = wv & 3;         // wave within group
    const int lane = tid & 63;
    const int lm = lane & 15;
    const int g  = lane >> 4;
    const int key = (lm & 7) << 4;
    const int jl = wl * 16 + lm;
    const int j  = jt * 64 + jl;

    __shared__ __align__(16) f16 VA0[64 * 64], VA1[64 * 64];   // group A V dbuf
    __shared__ __align__(16) f16 VB0[64 * 64], VB1[64 * 64];   // group B V dbuf
    __shared__ float MZ[128];                                  // merge m/z

    // per-lane staging source perm (pre-swizzle so linear LDS dest ends up XOR'd)
    const int rsub = lane >> 3;                 // row within 8-row segment
    const int perm = ((lane & 7) ^ rsub) << 3;  // f16 units
    const int seg = 2 * wl;
    const int ibase = ih * 2048;
    const f16* kS = kT + ((size_t)n * HW) * 64;
    const f16* vS = vv + ((size_t)n * CR) * HW;

    // running V prefetch pointers (tile 1 of this group's range)
    const f16* vp[2];
#pragma unroll
    for (int h = 0; h < 2; ++h) {
        const int q = seg + h;
        vp[h] = vS + (size_t)(q * 8 + rsub) * HW + ibase + 64 + perm;
    }

    // Q in regs: B-frag col=j, k(c) = ks*32 + g*8 + e
    f16x8 qf[2];
    {
        const f16* qp = qT + ((size_t)n * HW + j) * 64 + g * 8;
        qf[0] = *(const f16x8*)(qp);
        qf[1] = *(const f16x8*)(qp + 32);
    }

    float m = -1e30f, z = 0.f;
    f32x4 accp[4];
#pragma unroll
    for (int c = 0; c < 4; ++c) accp[c] = f32x4{0.f, 0.f, 0.f, 0.f};

    // prologue: stage V tile 0 of this group's range
    if (ih == 0) {
#pragma unroll
        for (int h = 0; h < 2; ++h) {
            const int q = seg + h;
            gl_lds16(vS + (size_t)(q * 8 + rsub) * HW + ibase + perm, &VA0[q * 512]);
        }
    } else {
#pragma unroll
        for (int h = 0; h < 2; ++h) {
            const int q = seg + h;
            gl_lds16(vS + (size_t)(q * 8 + rsub) * HW + ibase + perm, &VB0[q * 512]);
        }
    }
    __syncthreads();

#define ATTN_STEP(CV, NV, PF, I0)                                               \
    do {                                                                        \
        const char* Vb = (const char*)(CV);                                     \
        /* K A-frags straight from global (L2/L1) */                            \
        const f16* kb = kS + (size_t)(I0) * 64;                                 \
        f16x8 kf0[4], kf1[4];                                                   \
        _Pragma("unroll")                                                       \
        for (int f = 0; f < 4; ++f) {                                           \
            const f16* kr = kb + (f * 16 + lm) * 64 + g * 8;                    \
            kf0[f] = *(const f16x8*)(kr);                                       \
            kf1[f] = *(const f16x8*)(kr + 32);                                  \
        }                                                                       \
        f16x4 vf[4][4];                                                         \
        _Pragma("unroll")                                                       \
        for (int cf = 0; cf < 4; ++cf)                                          \
            _Pragma("unroll")                                                   \
            for (int f = 0; f < 4; ++f)                                         \
                vf[cf][f] = *(const f16x4*)(Vb + (cf * 16 + lm) * 128 +         \
                                            ((f * 32 + g * 8) ^ key));          \
        f32x4 sacc[4];                                                          \
        _Pragma("unroll")                                                       \
        for (int f = 0; f < 4; ++f) sacc[f] = f32x4{0.f, 0.f, 0.f, 0.f};        \
        __builtin_amdgcn_s_setprio(1);                                          \
        _Pragma("unroll")                                                       \
        for (int f = 0; f < 4; ++f) {                                           \
            sacc[f] = __builtin_amdgcn_mfma_f32_16x16x32_f16(kf0[f], qf[0], sacc[f], 0, 0, 0); \
            sacc[f] = __builtin_amdgcn_mfma_f32_16x16x32_f16(kf1[f], qf[1], sacc[f], 0, 0, 0); \
        }                                                                       \
        __builtin_amdgcn_s_setprio(0);                                          \
        if (PF) {                                                               \
            _Pragma("unroll")                                                   \
            for (int h = 0; h < 2; ++h) {                                       \
                const int q = seg + h;                                          \
                gl_lds16(vp[h], &(NV)[q * 512]); vp[h] += 64;                   \
            }                                                                   \
        }                                                                       \
        /* online softmax (exp2 domain), tree reductions */                     \
        float mA = fmaxf(fmaxf(sacc[0][0], sacc[0][1]), fmaxf(sacc[0][2], sacc[0][3])); \
        float mB = fmaxf(fmaxf(sacc[1][0], sacc[1][1]), fmaxf(sacc[1][2], sacc[1][3])); \
        float mC = fmaxf(fmaxf(sacc[2][0], sacc[2][1]), fmaxf(sacc[2][2], sacc[2][3])); \
        float mD = fmaxf(fmaxf(sacc[3][0], sacc[3][1]), fmaxf(sacc[3][2], sacc[3][3])); \
        float mt = fmaxf(fmaxf(mA, mB), fmaxf(mC, mD));                         \
        mt = fmaxf(mt, __shfl_xor(mt, 16));                                     \
        mt = fmaxf(mt, __shfl_xor(mt, 32));                                     \
        if (__ballot(mt > m)) {                                                 \
            const float mnew = fmaxf(m, mt);                                    \
            const float rsc = ex2(m - mnew);                                    \
            z *= rsc;                                                           \
            _Pragma("unroll")                                                   \
            for (int cf = 0; cf < 4; ++cf) {                                    \
                accp[cf][0] *= rsc; accp[cf][1] *= rsc;                         \
                accp[cf][2] *= rsc; accp[cf][3] *= rsc;                         \
            }                                                                   \
            m = mnew;                                                           \
        }                                                                       \
        f16x4 p16[4];                                                           \
        float zp[4];                                                            \
        _Pragma("unroll")                                                       \
        for (int f = 0; f < 4; ++f) {                                           \
            const float e0 = ex2(sacc[f][0] - m), e1 = ex2(sacc[f][1] - m);     \
            const float e2 = ex2(sacc[f][2] - m), e3 = ex2(sacc[f][3] - m);     \
            zp[f] = (e0 + e1) + (e2 + e3);                                      \
            p16[f][0] = (f16)e0; p16[f][1] = (f16)e1;                           \
            p16[f][2] = (f16)e2; p16[f][3] = (f16)e3;                           \
        }                                                                       \
        float zt = (zp[0] + zp[1]) + (zp[2] + zp[3]);                           \
        zt += __shfl_xor(zt, 16);                                               \
        zt += __shfl_xor(zt, 32);                                               \
        z += zt;                                                                \
        __builtin_amdgcn_s_setprio(1);                                          \
        _Pragma("unroll")                                                       \
        for (int cf = 0; cf < 4; ++cf)                                          \
            _Pragma("unroll")                                                   \
            for (int f = 0; f < 4; ++f)                                         \
                accp[cf] = __builtin_amdgcn_mfma_f32_16x16x16f16(               \
                    vf[cf][f], p16[f], accp[cf], 0, 0, 0);                      \
        __builtin_amdgcn_s_setprio(0);                                          \
        __syncthreads();                                                        \
    } while (0)

    // 32 tiles per group; both branches execute IDENTICAL barrier sequences
    if (ih == 0) {
        for (int itp = 0; itp < 16; ++itp) {
            ATTN_STEP(VA0, VA1, 1, ibase + itp * 128);
            ATTN_STEP(VA1, VA0, (itp < 15), ibase + itp * 128 + 64);
        }
    } else {
        for (int itp = 0; itp < 16; ++itp) {
            ATTN_STEP(VB0, VB1, 1, ibase + itp * 128);
            ATTN_STEP(VB1, VB0, (itp < 15), ibase + itp * 128 + 64);
        }
    }
#undef ATTN_STEP

    // ---- merge halves: group B publishes (m, z, acc) via LDS; group A combines
    if (ih == 1) {
        if (g == 0) {
            MZ[jl] = m;
            MZ[64 + jl] = z;
        }
        float* accdst = (wl < 2) ? (float*)VA0 : (float*)VA1;
        const int row = (wl & 1) * 16 + lm;
#pragma unroll
        for (int cf = 0; cf < 4; ++cf)
            *(f32x4*)(accdst + row * 64 + cf * 16 + g * 4) = accp[cf];
    }
    __syncthreads();
    if (ih == 0) {
        const float mO = MZ[jl];
        const float zO = MZ[64 + jl];
        const float* accsrc = (wl < 2) ? (const float*)VA0 : (const float*)VA1;
        const int row = (wl & 1) * 16 + lm;
        const float M = fmaxf(m, mO);
        const float rA = ex2(m - M);
        const float rB = ex2(mO - M);
        const float zz = z * rA + zO * rB;
        const size_t jbase = ((size_t)n * HW + j) * 64;
#pragma unroll
        for (int cf = 0; cf < 4; ++cf) {
            const f32x4 ab = *(const f32x4*)(accsrc + row * 64 + cf * 16 + g * 4);
            f16x4 pk;
#pragma unroll
            for (int e = 0; e < 4; ++e)
                pk[e] = (f16)(accp[cf][e] * rA + ab[e] * rB);
            *(f16x4*)(attu + jbase + cf * 16 + g * 4) = pk;
        }
        if (g == 0) {
            Mcol[(size_t)n * HW + j] = M;
            Zcol[(size_t)n * HW + j] = zz;
        }
    }
}

// ------------------------------------------------------------- global M, Z per n
__global__ __launch_bounds__(256) void reduce_kernel(
    const float* __restrict__ Mcol, const float* __restrict__ Zcol,
    float* __restrict__ Mn, float* __restrict__ Zn)
{
    const int n = blockIdx.x;
    const int tid = threadIdx.x;
    __shared__ float red[256];

    float lm = -1e30f;
    for (int j = tid; j < HW; j += 256) lm = fmaxf(lm, Mcol[(size_t)n * HW + j]);
    red[tid] = lm; __syncthreads();
    for (int s = 128; s > 0; s >>= 1) {
        if (tid < s) red[tid] = fmaxf(red[tid], red[tid + s]);
        __syncthreads();
    }
    const float M = red[0];
    __syncthreads();

    float ls = 0.f;
    for (int j = tid; j < HW; j += 256)
        ls += Zcol[(size_t)n * HW + j] * ex2(Mcol[(size_t)n * HW + j] - M);
    red[tid] = ls; __syncthreads();
    for (int s = 128; s > 0; s >>= 1) {
        if (tid < s) red[tid] += red[tid + s];
        __syncthreads();
    }
    if (tid == 0) { Mn[n] = M; Zn[n] = red[0]; }
}

// --------------------- MFMA 1x1 conv + per-column scale + elementwise
__global__ __launch_bounds__(512) void final_mfma(
    const f16* __restrict__ attu, const float* __restrict__ Mcol,
    const float* __restrict__ Mn, const float* __restrict__ Zn,
    const float* __restrict__ watt, const float* __restrict__ batt,
    const float* __restrict__ gco, float* __restrict__ out)
{
    __shared__ __align__(16) f16 Wl[256 * 64];   // 32 KB
    __shared__ __align__(16) f16 Al[128 * 64];   // 16 KB

    const int bid0 = blockIdx.x;
    const int bid = (bid0 & 7) * 32 + (bid0 >> 3);   // XCD swizzle: n == XCD
    const int n  = bid >> 5;
    const int p0 = (bid & 31) * 128;
    const int tid = threadIdx.x;
    const int wv = tid >> 6;
    const int lane = tid & 63;
    const int lm = lane & 15;
    const int g  = lane >> 4;

#pragma unroll
    for (int t = 0; t < 8; ++t) {
        const int idx = tid + t * 512;
        const int co = idx >> 4;
        const int ch = idx & 15;
        const float4 w4 = *(const float4*)(watt + (size_t)co * 64 + ch * 4);
        f16x4 pk;
        pk[0] = (f16)w4.x; pk[1] = (f16)w4.y; pk[2] = (f16)w4.z; pk[3] = (f16)w4.w;
        *(f16x4*)((char*)Wl + co * 128 + ((ch * 8) ^ ((co & 7) << 4))) = pk;
    }
#pragma unroll
    for (int t = 0; t < 4; ++t) {
        const int idx = tid + t * 512;
        const int pp = idx >> 3;
        const int ch = idx & 7;
        *(uint4*)((char*)Al + pp * 128 + ((ch * 16) ^ ((pp & 7) << 4))) =
            *(const uint4*)(attu + ((size_t)n * HW + p0 + pp) * 64 + ch * 8);
    }
    __syncthreads();

    f32x4 acc[2][8];
#pragma unroll
    for (int cf = 0; cf < 2; ++cf)
#pragma unroll
        for (int pf = 0; pf < 8; ++pf) acc[cf][pf] = f32x4{0.f, 0.f, 0.f, 0.f};

#pragma unroll
    for (int ks = 0; ks < 2; ++ks) {
        const int off = ks * 64 + g * 16;
        f16x8 A[2], B[8];
#pragma unroll
        for (int cf = 0; cf < 2; ++cf) {
            const int co = wv * 32 + cf * 16 + lm;
            A[cf] = *(const f16x8*)((char*)Wl + co * 128 + (off ^ ((co & 7) << 4)));
        }
#pragma unroll
        for (int pf = 0; pf < 8; ++pf) {
            const int pp = pf * 16 + lm;
            B[pf] = *(const f16x8*)((char*)Al + pp * 128 + (off ^ ((pp & 7) << 4)));
        }
#pragma unroll
        for (int cf = 0; cf < 2; ++cf)
#pragma unroll
            for (int pf = 0; pf < 8; ++pf)
                acc[cf][pf] = __builtin_amdgcn_mfma_f32_16x16x32_f16(
                    A[cf], B[pf], acc[cf][pf], 0, 0, 0);
    }

    const float M = Mn[n];
    const float Zi = 1.f / Zn[n];
    float ecol[8];
#pragma unroll
    for (int pf = 0; pf < 8; ++pf)
        ecol[pf] = ex2(Mcol[(size_t)n * HW + p0 + pf * 16 + lm] - M) * Zi;

#pragma unroll
    for (int cf = 0; cf < 2; ++cf) {
#pragma unroll
        for (int e = 0; e < 4; ++e) {
            const int co = wv * 32 + cf * 16 + g * 4 + e;
            const float bb = batt[co] + 1.f;
            const float* gsrc = gco + (size_t)(n * CIN + co) * HW + p0 + lm;
            float* dstp = out + (size_t)(n * CIN + co) * HW + p0 + lm;
#pragma unroll
            for (int pf = 0; pf < 8; ++pf) {
                const float gvv = gsrc[pf * 16];
                dstp[pf * 16] = gvv * (acc[cf][pf][e] * ecol[pf] + bb);
            }
        }
    }
}

// --------------------------------------------------------------------- launch
extern "C" void kernel_launch(void* const* d_in, const int* in_sizes, int n_in,
                              void* d_out, int out_size, void* d_ws, size_t ws_size,
                              hipStream_t stream)
{
    (void)in_sizes; (void)n_in; (void)out_size; (void)ws_size;
    const float* fm   = (const float*)d_in[0];
    const float* gco  = (const float*)d_in[1];
    const float* wq   = (const float*)d_in[2];
    const float* bq   = (const float*)d_in[3];
    const float* wk   = (const float*)d_in[4];
    const float* bk   = (const float*)d_in[5];
    const float* wv   = (const float*)d_in[6];
    const float* bv   = (const float*)d_in[7];
    const float* watt = (const float*)d_in[8];
    const float* batt = (const float*)d_in[9];
    float* out = (float*)d_out;

    // f16 scratch in d_out (28.8 MB of 33.5 MB): qT|kT|v|fmT, all dead before final.
    f16* qT   = (f16*)out;            // [n][p][c]   4 MB  (pre-scaled by log2e)
    f16* kT   = qT + QKV;             // [n][p][c]   4 MB
    f16* vvb  = kT + QKV;             // [n][c][p]   4 MB
    f16* fmT  = vvb + QKV;            // [n][p][ci]  16.8 MB

    // ws: wTq | wTk | wTv | attu | Mcol | Zcol | Mn | Zn  (7.18 MB, proven layout)
    unsigned char* wsb = (unsigned char*)d_ws;
    f16* wTq = (f16*)(wsb);
    f16* wTk = (f16*)(wsb + 294912);
    f16* wTv = (f16*)(wsb + 1114112);
    f16* attu = (f16*)(wsb + 2719744);                        // [n][p][c] f16, 4 MB
    float* Mcol = (float*)(wsb + 6914048);                    // [n][4096] f32 (log2)
    float* Zcol = (float*)(wsb + 7045120);
    float* Mn   = (float*)(wsb + 7176192);
    float* Zn   = (float*)(wsb + 7176224);

    const float LOG2E = 1.4426950408889634f;

    prep_w<<<576, 256, 0, stream>>>(wq, wTq, 9);
    prep_w<<<1600, 256, 0, stream>>>(wk, wTk, 25);
    prep_w<<<3136, 256, 0, stream>>>(wv, wTv, 49);
    transpose_fm<<<NB * 64, 256, 0, stream>>>(fm, fmT);

    conv_mfma<3, 0><<<256, 512, 0, stream>>>(fmT, wTq, bq, qT, LOG2E);
    conv_mfma<5, 0><<<256, 512, 0, stream>>>(fmT, wTk, bk, kT, 1.0f);
    conv_mfma<7, 1><<<256, 512, 0, stream>>>(fmT, wTv, bv, vvb, 1.0f);

    attn_mfma<<<NB * 64, 512, 0, stream>>>(qT, kT, vvb, attu, Mcol, Zcol);
    reduce_kernel<<<NB, 256, 0, stream>>>(Mcol, Zcol, Mn, Zn);
    final_mfma<<<256, 512, 0, stream>>>(attu, Mcol, Mn, Zn, watt, batt, gco, out);
}

// Round 12
// 220.908 us; speedup vs baseline: 1.2868x; 1.2868x over previous
//
#include <hip/hip_runtime.h>
#include <math.h>

#define NB 8
#define CIN 256
#define CR 64
#define H 64
#define W 64
#define HW 4096

typedef _Float16 f16;
typedef _Float16 f16x8 __attribute__((ext_vector_type(8)));
typedef _Float16 f16x4 __attribute__((ext_vector_type(4)));
typedef float f32x4 __attribute__((ext_vector_type(4)));

static const size_t QKV = (size_t)NB * CR * HW;   // 2,097,152 elems per q/k/v buffer

// raw v_exp_f32 (exp2); inputs <= 0 here, denorm tail irrelevant
static __device__ __forceinline__ float ex2(float x) {
    return __builtin_amdgcn_exp2f(x);
}

// ------------------------------------------------------------- weight prep
// w[co][ci][dy][dx] fp32 -> wT[dy*K+dx][co][ci] fp16   (all three in one grid)
__global__ __launch_bounds__(256) void prep_all(
    const float* __restrict__ wq, const float* __restrict__ wk,
    const float* __restrict__ wv,
    f16* __restrict__ dq, f16* __restrict__ dk, f16* __restrict__ dv)
{
    int b = blockIdx.x;
    const float* src; f16* dst; int KK;
    if (b < 576)       { src = wq; dst = dq; KK = 9; }
    else if (b < 2176) { src = wk; dst = dk; KK = 25; b -= 576; }
    else               { src = wv; dst = dv; KK = 49; b -= 2176; }
    int idx = b * 256 + threadIdx.x;
    int ci = idx & 255;
    int co = (idx >> 8) & 63;
    int off = idx >> 14;
    dst[((size_t)(off * 64 + co)) * 256 + ci] = (f16)src[((size_t)(co * 256 + ci)) * KK + off];
}

// ------------------------------------------------------- feature-map transpose
// fm f32 [n][ci][y][x] -> fmT f16 [n][y*64+x][ci]
__global__ __launch_bounds__(256) void transpose_fm(
    const float* __restrict__ fm, f16* __restrict__ fmT)
{
    const int y = blockIdx.x & 63;
    const int n = blockIdx.x >> 6;
    const int tid = threadIdx.x;
    __shared__ f16x4 tile[64 * 64];   // [x][slot], slot XOR-swizzled by x
    const int xw = tid & 63;
    const int wv = tid >> 6;
    const float* s0 = fm + ((size_t)n * CIN) * HW + y * W + xw;
#pragma unroll
    for (int cc = 0; cc < 16; ++cc) {
        const int slot = wv * 16 + cc;            // ci = slot*4 + e
        const float* s = s0 + (size_t)(slot * 4) * HW;
        f16x4 pk;
#pragma unroll
        for (int e = 0; e < 4; ++e) pk[e] = (f16)s[(size_t)e * HW];
        tile[xw * 64 + (slot ^ xw)] = pk;
    }
    __syncthreads();
    f16x4* dst = (f16x4*)fmT + ((size_t)n * HW + y * W) * 64;
#pragma unroll
    for (int it = 0; it < 16; ++it) {
        const int idx = tid + it * 256;           // < 4096
        const int x = idx >> 6;
        const int slot = idx & 63;
        dst[x * 64 + slot] = tile[x * 64 + (slot ^ x)];
    }
}

// ---------------------------------------------------------- MFMA conv K x K body
// 512 threads = 8 waves (row r, co-half h, k-half sw). 2-row group per block.
// LAYOUT 0: dst [n][p][c] f16 (q, k).  LAYOUT 1: dst [n][c][p] f16 (v).
template<int K, int LAYOUT>
static __device__ __forceinline__ void conv_body(
    const f16* __restrict__ fmT, const f16* __restrict__ wT,
    const float* __restrict__ bias, f16* __restrict__ dst, float oscale,
    unsigned char* smem, int bid0)
{
    constexpr int P = K / 2;
    constexpr int XBYTES = 2 * 72 * 128;          // 18432
    unsigned char* Xl = smem;
    unsigned char* Wl = smem + XBYTES;

    const int bid = (bid0 & 7) * 32 + (bid0 >> 3);   // XCD swizzle, 256 = 8*32
    const int n  = bid >> 5;
    const int y0 = (bid & 31) * 2;
    const int tid = threadIdx.x;
    const int w = tid >> 6;
    const int lane = tid & 63;
    const int r  = w >> 2;        // row within block
    const int h  = (w >> 1) & 1;  // co half
    const int sw = w & 1;         // k half (32-ci sub-chunk)
    const int lm = lane & 15;
    const int g  = lane >> 4;

    // zero halo columns once (cols [0,P) and [64+P,72) of both slots)
    if (tid < 128) {
        const int sl = tid >> 6;
        const int cidx = (tid >> 3) & 7;
        const int chunk = tid & 7;
        const int col = (cidx < P) ? cidx : (64 + cidx);
        *(uint4*)(Xl + (size_t)(sl * 72 + col) * 128 + chunk * 16) = uint4{0, 0, 0, 0};
    }

    f32x4 acc[2][4];
#pragma unroll
    for (int i = 0; i < 2; ++i)
#pragma unroll
        for (int jx = 0; jx < 4; ++jx) acc[i][jx] = f32x4{0.f, 0.f, 0.f, 0.f};

    for (int dy = 0; dy < K; ++dy) {
        for (int ch = 0; ch < 4; ++ch) {
            __syncthreads();
            // ---- stage X: 2 rows x 64 x x 64 ci(ch) = 1024 uint4, 2/thread
#pragma unroll
            for (int p = 0; p < 2; ++p) {
                const int idx = tid + p * 512;
                const int sl = idx >> 9;
                const int x = (idx >> 3) & 63;
                const int chunk = idx & 7;
                const int iy = y0 + sl + dy - P;
                uint4 val = uint4{0, 0, 0, 0};
                if (iy >= 0 && iy < H)
                    val = *(const uint4*)(fmT + ((size_t)n * HW + iy * 64 + x) * 256 +
                                          ch * 64 + chunk * 8);
                *(uint4*)(Xl + (size_t)(sl * 72 + x + P) * 128 +
                          ((chunk * 16) ^ (((x + P) & 7) << 4))) = val;
            }
            // ---- stage W: K*512 uint4, K/thread
#pragma unroll
            for (int p = 0; p < K; ++p) {
                const int idx = tid + p * 512;
                const int cig = idx & 7;
                const int co  = (idx >> 3) & 63;
                const int dx  = idx >> 9;
                const f16* s = wT + ((size_t)((dy * K + dx) * 64 + co)) * 256 + ch * 64 + cig * 8;
                *(uint4*)(Wl + (size_t)(dx * 64 + co) * 128 +
                          ((cig * 16) ^ ((co & 7) << 4))) = *(const uint4*)s;
            }
            __syncthreads();
            // ---- compute
#pragma unroll
            for (int dx = 0; dx < K; ++dx) {
                f16x8 a[2], b[4];
#pragma unroll
                for (int cf = 0; cf < 2; ++cf) {
                    const int co = h * 32 + cf * 16 + lm;
                    a[cf] = *(const f16x8*)(Wl + (size_t)(dx * 64 + co) * 128 +
                                            ((sw * 64 + g * 16) ^ ((co & 7) << 4)));
                }
#pragma unroll
                for (int xf = 0; xf < 4; ++xf) {
                    const int col = xf * 16 + lm + dx;
                    b[xf] = *(const f16x8*)(Xl + (size_t)(r * 72 + col) * 128 +
                                            ((sw * 64 + g * 16) ^ ((col & 7) << 4)));
                }
#pragma unroll
                for (int cf = 0; cf < 2; ++cf)
#pragma unroll
                    for (int xf = 0; xf < 4; ++xf)
                        acc[cf][xf] = __builtin_amdgcn_mfma_f32_16x16x32_f16(
                            a[cf], b[xf], acc[cf][xf], 0, 0, 0);
            }
        }
    }

    // ---- merge k-halves
    __syncthreads();
    {
        const int mslot = r * 2 + h;
        if (sw == 1) {
#pragma unroll
            for (int cf = 0; cf < 2; ++cf)
#pragma unroll
                for (int xf = 0; xf < 4; ++xf)
                    *(f32x4*)(smem + (size_t)(mslot * 64 + lane) * 128 +
                              (((cf * 4 + xf) * 16) ^ ((lane & 7) << 4))) = acc[cf][xf];
        }
        __syncthreads();
        if (sw == 0) {
#pragma unroll
            for (int cf = 0; cf < 2; ++cf)
#pragma unroll
                for (int xf = 0; xf < 4; ++xf)
                    acc[cf][xf] += *(const f32x4*)(smem + (size_t)(mslot * 64 + lane) * 128 +
                                                   (((cf * 4 + xf) * 16) ^ ((lane & 7) << 4)));
        }
    }

    // ---- epilogue (sw=0 waves)
    if (sw == 0) {
        const int y = y0 + r;
#pragma unroll
        for (int cf = 0; cf < 2; ++cf) {
            const float4 bv = *(const float4*)(bias + h * 32 + cf * 16 + g * 4);
            if (LAYOUT == 0) {
#pragma unroll
                for (int xf = 0; xf < 4; ++xf) {
                    f16x4 pk;
#pragma unroll
                    for (int e = 0; e < 4; ++e)
                        pk[e] = (f16)((acc[cf][xf][e] + ((const float*)&bv)[e]) * oscale);
                    *(f16x4*)(dst + ((size_t)n * HW + y * W + xf * 16 + lm) * 64 +
                              h * 32 + cf * 16 + g * 4) = pk;
                }
            } else {
#pragma unroll
                for (int e = 0; e < 4; ++e) {
                    const int co = h * 32 + cf * 16 + g * 4 + e;
#pragma unroll
                    for (int xf = 0; xf < 4; ++xf)
                        dst[((size_t)(n * CR + co)) * HW + y * W + xf * 16 + lm] =
                            (f16)((acc[cf][xf][e] + ((const float*)&bv)[e]) * oscale);
                }
            }
        }
    }
}

// All three convs in one launch (768 blocks) so they overlap and fill the GPU.
__global__ __launch_bounds__(512) void conv_all(
    const f16* __restrict__ fmT,
    const f16* __restrict__ wTq, const f16* __restrict__ wTk, const f16* __restrict__ wTv,
    const float* __restrict__ bq, const float* __restrict__ bk, const float* __restrict__ bv,
    f16* __restrict__ qT, f16* __restrict__ kT, f16* __restrict__ vvb, float log2e)
{
    __shared__ __align__(16) unsigned char smem[2 * 72 * 128 + 7 * 64 * 128];  // 75776 (K=7)
    const int b = blockIdx.x;
    if (b < 256)      conv_body<3, 0>(fmT, wTq, bq, qT, log2e, smem, b);
    else if (b < 512) conv_body<5, 0>(fmT, wTk, bk, kT, 1.0f, smem, b - 256);
    else              conv_body<7, 1>(fmT, wTv, bv, vvb, 1.0f, smem, b - 512);
}

// ------------------------------------------------- fused MFMA attention (16x16)
// EXACT r5 structure (proven 86 us): grid 512 (n, 64-j tile), 4 waves; wave owns
// 16 j; Qt/Kt/Vt single-buffered in LDS via register staging; 2 barriers/step.
// Only mods: exp2-domain softmax (q pre-scaled log2e), defer-max, tree reductions.
__global__ __launch_bounds__(256, 2) void attn_mfma(
    const f16* __restrict__ qT, const f16* __restrict__ kT, const f16* __restrict__ vv,
    f16* __restrict__ attu, float* __restrict__ Mcol, float* __restrict__ Zcol)
{
    const int bid0 = blockIdx.x;
    const int bid = (bid0 & 7) * 64 + (bid0 >> 3);   // XCD swizzle, 512 = 8*64
    const int jt = bid & 63;
    const int n  = bid >> 6;
    const int j0 = jt * 64;
    const int tid = threadIdx.x;
    const int wv = tid >> 6;
    const int lane = tid & 63;
    const int lm = lane & 15;
    const int g  = lane >> 4;
    const int key = (lm & 7) << 4;

    __shared__ __align__(16) f16 Qt[64 * 64];
    __shared__ __align__(16) f16 Kt[64 * 64];
    __shared__ __align__(16) f16 Vt[64 * 64];

    // stage Qt once: qT[n][j0+j][c] -> rows [j][64c], XOR-swizzled 16B slots
    {
        const int r = tid >> 2;
        const f16* src = qT + ((size_t)n * HW + j0 + r) * 64;
#pragma unroll
        for (int h = 0; h < 2; ++h) {
            const int ch = (tid & 3) * 2 + h;
            *(uint4*)((char*)Qt + r * 128 + ((ch * 16) ^ ((r & 7) << 4))) =
                *(const uint4*)(src + ch * 8);
        }
    }

    float m = -1e30f, z = 0.f;
    f32x4 accp[4];
#pragma unroll
    for (int c = 0; c < 4; ++c) accp[c] = f32x4{0.f, 0.f, 0.f, 0.f};

    for (int it = 0; it < 64; ++it) {
        const int i0 = it * 64;
        __syncthreads();
        // stage Kt ([i][c]) and Vt ([c][i])
        {
            const int r = tid >> 2;
            const f16* ks = kT + ((size_t)n * HW + i0 + r) * 64;
            const f16* vs = vv + ((size_t)n * CR + r) * HW + i0;
#pragma unroll
            for (int h = 0; h < 2; ++h) {
                const int ch = (tid & 3) * 2 + h;
                *(uint4*)((char*)Kt + r * 128 + ((ch * 16) ^ ((r & 7) << 4))) =
                    *(const uint4*)(ks + ch * 8);
                *(uint4*)((char*)Vt + r * 128 + ((ch * 16) ^ ((r & 7) << 4))) =
                    *(const uint4*)(vs + ch * 8);
            }
        }
        __syncthreads();

        // ---- QK: S[i][j], wave covers 64 i (4 frags) x its 16 j
        f32x4 sacc[4];
#pragma unroll
        for (int f = 0; f < 4; ++f) sacc[f] = f32x4{0.f, 0.f, 0.f, 0.f};
#pragma unroll
        for (int ks2 = 0; ks2 < 2; ++ks2) {
            const int off = (ks2 * 64 + g * 16);
            const f16x8 B = *(const f16x8*)((char*)Qt + (wv * 16 + lm) * 128 + (off ^ key));
#pragma unroll
            for (int f = 0; f < 4; ++f) {
                const f16x8 A = *(const f16x8*)((char*)Kt + (f * 16 + lm) * 128 + (off ^ key));
                sacc[f] = __builtin_amdgcn_mfma_f32_16x16x32_f16(A, B, sacc[f], 0, 0, 0);
            }
        }

        // ---- online softmax (exp2 domain); tree max, defer-max
        const float mA = fmaxf(fmaxf(sacc[0][0], sacc[0][1]), fmaxf(sacc[0][2], sacc[0][3]));
        const float mB = fmaxf(fmaxf(sacc[1][0], sacc[1][1]), fmaxf(sacc[1][2], sacc[1][3]));
        const float mC = fmaxf(fmaxf(sacc[2][0], sacc[2][1]), fmaxf(sacc[2][2], sacc[2][3]));
        const float mD = fmaxf(fmaxf(sacc[3][0], sacc[3][1]), fmaxf(sacc[3][2], sacc[3][3]));
        float mt = fmaxf(fmaxf(mA, mB), fmaxf(mC, mD));
        mt = fmaxf(mt, __shfl_xor(mt, 16));
        mt = fmaxf(mt, __shfl_xor(mt, 32));
        if (__ballot(mt > m)) {        // defer-max: skip rescale when no column grew
            const float mnew = fmaxf(m, mt);
            const float rsc = ex2(m - mnew);
            z *= rsc;
#pragma unroll
            for (int cf = 0; cf < 4; ++cf) {
                accp[cf][0] *= rsc; accp[cf][1] *= rsc;
                accp[cf][2] *= rsc; accp[cf][3] *= rsc;
            }
            m = mnew;
        }
        f16x4 p16[4];
        float zp[4];
#pragma unroll
        for (int f = 0; f < 4; ++f) {
            const float e0 = ex2(sacc[f][0] - m), e1 = ex2(sacc[f][1] - m);
            const float e2 = ex2(sacc[f][2] - m), e3 = ex2(sacc[f][3] - m);
            zp[f] = (e0 + e1) + (e2 + e3);
            p16[f][0] = (f16)e0; p16[f][1] = (f16)e1;
            p16[f][2] = (f16)e2; p16[f][3] = (f16)e3;
        }
        float zt = (zp[0] + zp[1]) + (zp[2] + zp[3]);
        zt += __shfl_xor(zt, 16);
        zt += __shfl_xor(zt, 32);
        z += zt;

        // ---- PV: att[c][j] += V[c][i-tile] * P (k=16 frags, shuffle-free)
#pragma unroll
        for (int cf = 0; cf < 4; ++cf) {
#pragma unroll
            for (int f = 0; f < 4; ++f) {
                const f16x4 A = *(const f16x4*)((char*)Vt + (cf * 16 + lm) * 128 +
                                                ((f * 32 + g * 8) ^ key));
                accp[cf] = __builtin_amdgcn_mfma_f32_16x16x16f16(A, p16[f], accp[cf], 0, 0, 0);
            }
        }
    }

    // epilogue: attu[n][j][c] f16; Mcol/Zcol[n][j] (log2 domain)
    const int j = j0 + wv * 16 + lm;
    const size_t jbase = ((size_t)n * HW + j) * 64;
#pragma unroll
    for (int cf = 0; cf < 4; ++cf) {
        f16x4 pk;
#pragma unroll
        for (int e = 0; e < 4; ++e) pk[e] = (f16)accp[cf][e];
        *(f16x4*)(attu + jbase + cf * 16 + g * 4) = pk;
    }
    if (g == 0) {
        Mcol[(size_t)n * HW + j] = m;
        Zcol[(size_t)n * HW + j] = z;
    }
}

// ------------------------------------------------------------- global M, Z per n
__global__ __launch_bounds__(256) void reduce_kernel(
    const float* __restrict__ Mcol, const float* __restrict__ Zcol,
    float* __restrict__ Mn, float* __restrict__ Zn)
{
    const int n = blockIdx.x;
    const int tid = threadIdx.x;
    __shared__ float red[256];

    float lm = -1e30f;
    for (int j = tid; j < HW; j += 256) lm = fmaxf(lm, Mcol[(size_t)n * HW + j]);
    red[tid] = lm; __syncthreads();
    for (int s = 128; s > 0; s >>= 1) {
        if (tid < s) red[tid] = fmaxf(red[tid], red[tid + s]);
        __syncthreads();
    }
    const float M = red[0];
    __syncthreads();

    float ls = 0.f;
    for (int j = tid; j < HW; j += 256)
        ls += Zcol[(size_t)n * HW + j] * ex2(Mcol[(size_t)n * HW + j] - M);
    red[tid] = ls; __syncthreads();
    for (int s = 128; s > 0; s >>= 1) {
        if (tid < s) red[tid] += red[tid + s];
        __syncthreads();
    }
    if (tid == 0) { Mn[n] = M; Zn[n] = red[0]; }
}

// --------------------- MFMA 1x1 conv + per-column scale + elementwise
__global__ __launch_bounds__(512) void final_mfma(
    const f16* __restrict__ attu, const float* __restrict__ Mcol,
    const float* __restrict__ Mn, const float* __restrict__ Zn,
    const float* __restrict__ watt, const float* __restrict__ batt,
    const float* __restrict__ gco, float* __restrict__ out)
{
    __shared__ __align__(16) f16 Wl[256 * 64];   // 32 KB
    __shared__ __align__(16) f16 Al[128 * 64];   // 16 KB

    const int bid0 = blockIdx.x;
    const int bid = (bid0 & 7) * 32 + (bid0 >> 3);   // XCD swizzle: n == XCD
    const int n  = bid >> 5;
    const int p0 = (bid & 31) * 128;
    const int tid = threadIdx.x;
    const int wv = tid >> 6;
    const int lane = tid & 63;
    const int lm = lane & 15;
    const int g  = lane >> 4;

#pragma unroll
    for (int t = 0; t < 8; ++t) {
        const int idx = tid + t * 512;
        const int co = idx >> 4;
        const int ch = idx & 15;
        const float4 w4 = *(const float4*)(watt + (size_t)co * 64 + ch * 4);
        f16x4 pk;
        pk[0] = (f16)w4.x; pk[1] = (f16)w4.y; pk[2] = (f16)w4.z; pk[3] = (f16)w4.w;
        *(f16x4*)((char*)Wl + co * 128 + ((ch * 8) ^ ((co & 7) << 4))) = pk;
    }
#pragma unroll
    for (int t = 0; t < 4; ++t) {
        const int idx = tid + t * 512;
        const int pp = idx >> 3;
        const int ch = idx & 7;
        *(uint4*)((char*)Al + pp * 128 + ((ch * 16) ^ ((pp & 7) << 4))) =
            *(const uint4*)(attu + ((size_t)n * HW + p0 + pp) * 64 + ch * 8);
    }
    __syncthreads();

    f32x4 acc[2][8];
#pragma unroll
    for (int cf = 0; cf < 2; ++cf)
#pragma unroll
        for (int pf = 0; pf < 8; ++pf) acc[cf][pf] = f32x4{0.f, 0.f, 0.f, 0.f};

#pragma unroll
    for (int ks = 0; ks < 2; ++ks) {
        const int off = ks * 64 + g * 16;
        f16x8 A[2], B[8];
#pragma unroll
        for (int cf = 0; cf < 2; ++cf) {
            const int co = wv * 32 + cf * 16 + lm;
            A[cf] = *(const f16x8*)((char*)Wl + co * 128 + (off ^ ((co & 7) << 4)));
        }
#pragma unroll
        for (int pf = 0; pf < 8; ++pf) {
            const int pp = pf * 16 + lm;
            B[pf] = *(const f16x8*)((char*)Al + pp * 128 + (off ^ ((pp & 7) << 4)));
        }
#pragma unroll
        for (int cf = 0; cf < 2; ++cf)
#pragma unroll
            for (int pf = 0; pf < 8; ++pf)
                acc[cf][pf] = __builtin_amdgcn_mfma_f32_16x16x32_f16(
                    A[cf], B[pf], acc[cf][pf], 0, 0, 0);
    }

    const float M = Mn[n];
    const float Zi = 1.f / Zn[n];
    float ecol[8];
#pragma unroll
    for (int pf = 0; pf < 8; ++pf)
        ecol[pf] = ex2(Mcol[(size_t)n * HW + p0 + pf * 16 + lm] - M) * Zi;

#pragma unroll
    for (int cf = 0; cf < 2; ++cf) {
#pragma unroll
        for (int e = 0; e < 4; ++e) {
            const int co = wv * 32 + cf * 16 + g * 4 + e;
            const float bb = batt[co] + 1.f;
            const float* gsrc = gco + (size_t)(n * CIN + co) * HW + p0 + lm;
            float* dstp = out + (size_t)(n * CIN + co) * HW + p0 + lm;
#pragma unroll
            for (int pf = 0; pf < 8; ++pf) {
                const float gvv = gsrc[pf * 16];
                dstp[pf * 16] = gvv * (acc[cf][pf][e] * ecol[pf] + bb);
            }
        }
    }
}

// --------------------------------------------------------------------- launch
extern "C" void kernel_launch(void* const* d_in, const int* in_sizes, int n_in,
                              void* d_out, int out_size, void* d_ws, size_t ws_size,
                              hipStream_t stream)
{
    (void)in_sizes; (void)n_in; (void)out_size; (void)ws_size;
    const float* fm   = (const float*)d_in[0];
    const float* gco  = (const float*)d_in[1];
    const float* wq   = (const float*)d_in[2];
    const float* bq   = (const float*)d_in[3];
    const float* wk   = (const float*)d_in[4];
    const float* bk   = (const float*)d_in[5];
    const float* wv   = (const float*)d_in[6];
    const float* bv   = (const float*)d_in[7];
    const float* watt = (const float*)d_in[8];
    const float* batt = (const float*)d_in[9];
    float* out = (float*)d_out;

    // f16 scratch in d_out (28.8 MB of 33.5 MB): qT|kT|v|fmT, all dead before final.
    f16* qT   = (f16*)out;            // [n][p][c]   4 MB  (pre-scaled by log2e)
    f16* kT   = qT + QKV;             // [n][p][c]   4 MB
    f16* vvb  = kT + QKV;             // [n][c][p]   4 MB
    f16* fmT  = vvb + QKV;            // [n][p][ci]  16.8 MB

    // ws: wTq | wTk | wTv | attu | Mcol | Zcol | Mn | Zn  (7.18 MB, proven layout)
    unsigned char* wsb = (unsigned char*)d_ws;
    f16* wTq = (f16*)(wsb);
    f16* wTk = (f16*)(wsb + 294912);
    f16* wTv = (f16*)(wsb + 1114112);
    f16* attu = (f16*)(wsb + 2719744);                        // [n][p][c] f16, 4 MB
    float* Mcol = (float*)(wsb + 6914048);                    // [n][4096] f32 (log2)
    float* Zcol = (float*)(wsb + 7045120);
    float* Mn   = (float*)(wsb + 7176192);
    float* Zn   = (float*)(wsb + 7176224);

    const float LOG2E = 1.4426950408889634f;

    prep_all<<<5312, 256, 0, stream>>>(wq, wk, wv, wTq, wTk, wTv);
    transpose_fm<<<NB * 64, 256, 0, stream>>>(fm, fmT);

    conv_all<<<768, 512, 0, stream>>>(fmT, wTq, wTk, wTv, bq, bk, bv,
                                      qT, kT, vvb, LOG2E);

    attn_mfma<<<NB * 64, 256, 0, stream>>>(qT, kT, vvb, attu, Mcol, Zcol);
    reduce_kernel<<<NB, 256, 0, stream>>>(Mcol, Zcol, Mn, Zn);
    final_mfma<<<256, 512, 0, stream>>>(attu, Mcol, Mn, Zn, watt, batt, gco, out);
}